// Round 7
// baseline (26.644 us; speedup 1.0000x reference)
//
#include <hip/hip_runtime.h>
#include <hip/hip_bf16.h>

// Problem: B=16, N=256, F=64, H=64
// out[b,i,j] = (i==j) ? 1 : sigmoid( sum_h relu(a[b,i,h]+c[b,j,h]) * w2[h] + b2 )
// a = hs @ w1[:, :64]^T + b1, c = hs @ w1[:, 64:]^T
//
// Round-7: ONE kernel node (two-node graphs cost ~10us drain on this stack).
// 64x64 (i,j) tiles, grid (4,4,16)=256 blocks. Phase 1 recomputes this
// block's a/c tiles (x4 redundancy, ~1.7us device FMA floor) with hs from
// swizzled LDS and w1 via the proven 4-lines-per-wave-instr global pattern.
// Phase 2 = r6's 4x4-blocked pair body. LDS = 32 KB.

#define Nn 256
#define Fd 64
#define Hd 64

__global__ __launch_bounds__(256) void fused_kernel(
    const float* __restrict__ hs, const float* __restrict__ w1,
    const float* __restrict__ b1, const float* __restrict__ w2,
    const float* __restrict__ b2, float* __restrict__ out) {
  // [0] = i-tile, [1] = j-tile. Holds staged hs rows, then a/c results.
  // Swizzle throughout: element [r][q] stored at col q ^ ((r>>2)&15).
  __shared__ float4 T4[2][64][16];

  const int t  = threadIdx.x;
  const int b  = blockIdx.z;
  const int i0 = blockIdx.y * 64;
  const int j0 = blockIdx.x * 64;

  // ---- Stage hs i-tile and j-tile (16 KB each), coalesced, swizzled ----
  {
    const float4* hsi4 = (const float4*)(hs + (size_t)(b * Nn + i0) * Fd);
    const float4* hsj4 = (const float4*)(hs + (size_t)(b * Nn + j0) * Fd);
#pragma unroll
    for (int p = 0; p < 4; ++p) {
      const int k = t + 256 * p;            // 0..1023
      const int r = k >> 4, q = k & 15;
      const int cs = q ^ (r >> 2);          // (r>>2)&15 == r>>2 for r<64
      T4[0][r][cs] = hsi4[k];
      T4[1][r][cs] = hsj4[k];
    }
  }
  __syncthreads();

  // ---- Phase 1: waves 0-1 -> a-tile (from hs_i), waves 2-3 -> c-tile ----
  // thread: 4 rows (rg*4+u) x 8 houts (hg*8+k).
  const int half = t >> 7;                  // 0=a, 1=c (wave-uniform)
  const int bidx = t & 127;
  const int rg = bidx & 15;                 // row-group
  const int hg = bidx >> 4;                 // h-group 0..7

  float acc1[4][8];
#pragma unroll
  for (int u = 0; u < 4; ++u)
#pragma unroll
    for (int k = 0; k < 8; ++k) acc1[u][k] = 0.f;

  {
    // w1 row pitch = 32 float4; a-part cols [0,16), c-part [16,32).
    const float4* w1p = (const float4*)w1 + half * (Fd / 4);
#pragma unroll
    for (int f4 = 0; f4 < 16; ++f4) {
      float4 hv[4];
#pragma unroll
      for (int u = 0; u < 4; ++u)
        hv[u] = T4[half][rg * 4 + u][f4 ^ rg];   // 16 distinct cols -> free
      float4 wv[8];
#pragma unroll
      for (int k = 0; k < 8; ++k)
        wv[k] = w1p[(size_t)(hg * 8 + k) * 32 + f4];  // 4 lines/wave-instr
#pragma unroll
      for (int u = 0; u < 4; ++u)
#pragma unroll
        for (int k = 0; k < 8; ++k) {
          acc1[u][k] = fmaf(hv[u].x, wv[k].x, acc1[u][k]);
          acc1[u][k] = fmaf(hv[u].y, wv[k].y, acc1[u][k]);
          acc1[u][k] = fmaf(hv[u].z, wv[k].z, acc1[u][k]);
          acc1[u][k] = fmaf(hv[u].w, wv[k].w, acc1[u][k]);
        }
    }
    if (half == 0) {
      const float4 bb0 = ((const float4*)b1)[hg * 2 + 0];
      const float4 bb1 = ((const float4*)b1)[hg * 2 + 1];
#pragma unroll
      for (int u = 0; u < 4; ++u) {
        acc1[u][0] += bb0.x; acc1[u][1] += bb0.y;
        acc1[u][2] += bb0.z; acc1[u][3] += bb0.w;
        acc1[u][4] += bb1.x; acc1[u][5] += bb1.y;
        acc1[u][6] += bb1.z; acc1[u][7] += bb1.w;
      }
    }
  }

  __syncthreads();   // all hs reads complete before overwrite

  // Write a/c results into the same region, phase-2 swizzle (col = h4 ^ rg).
#pragma unroll
  for (int u = 0; u < 4; ++u) {
    const int r = rg * 4 + u;
    T4[half][r][(hg * 2 + 0) ^ rg] =
        make_float4(acc1[u][0], acc1[u][1], acc1[u][2], acc1[u][3]);
    T4[half][r][(hg * 2 + 1) ^ rg] =
        make_float4(acc1[u][4], acc1[u][5], acc1[u][6], acc1[u][7]);
  }
  __syncthreads();

  // ---- Phase 2: pairwise logits + sigmoid (r6 4x4 body) ----
  float4 w2r[16];
#pragma unroll
  for (int q = 0; q < 16; ++q) w2r[q] = ((const float4*)w2)[q];  // uniform
  const float bias2 = b2[0];

  const int it = t >> 4;
  const int jt = t & 15;
  const int ib = it * 4;
  const int jb = jt * 4;

  float acc[4][4];
#pragma unroll
  for (int u = 0; u < 4; ++u)
#pragma unroll
    for (int v = 0; v < 4; ++v) acc[u][v] = 0.f;

#pragma unroll
  for (int h4 = 0; h4 < 16; ++h4) {
    const float4 ww = w2r[h4];
    float4 aa[4], cc[4];
#pragma unroll
    for (int u = 0; u < 4; ++u) aa[u] = T4[0][ib + u][h4 ^ it];
#pragma unroll
    for (int v = 0; v < 4; ++v) cc[v] = T4[1][jb + v][h4 ^ jt];

#pragma unroll
    for (int u = 0; u < 4; ++u)
#pragma unroll
      for (int v = 0; v < 4; ++v) {
        acc[u][v] = fmaf(fmaxf(aa[u].x + cc[v].x, 0.f), ww.x, acc[u][v]);
        acc[u][v] = fmaf(fmaxf(aa[u].y + cc[v].y, 0.f), ww.y, acc[u][v]);
        acc[u][v] = fmaf(fmaxf(aa[u].z + cc[v].z, 0.f), ww.z, acc[u][v]);
        acc[u][v] = fmaf(fmaxf(aa[u].w + cc[v].w, 0.f), ww.w, acc[u][v]);
      }
  }

#pragma unroll
  for (int u = 0; u < 4; ++u) {
    const int i = i0 + ib + u;
    float4 o;
    o.x = (i == j0 + jb + 0) ? 1.0f : 1.f / (1.f + __expf(-(acc[u][0] + bias2)));
    o.y = (i == j0 + jb + 1) ? 1.0f : 1.f / (1.f + __expf(-(acc[u][1] + bias2)));
    o.z = (i == j0 + jb + 2) ? 1.0f : 1.f / (1.f + __expf(-(acc[u][2] + bias2)));
    o.w = (i == j0 + jb + 3) ? 1.0f : 1.f / (1.f + __expf(-(acc[u][3] + bias2)));
    // coalesced: 16 consecutive float4 per 16-lane group
    ((float4*)(out + (size_t)(b * Nn + i) * Nn + j0))[jt] = o;
  }
}

extern "C" void kernel_launch(void* const* d_in, const int* in_sizes, int n_in,
                              void* d_out, int out_size, void* d_ws, size_t ws_size,
                              hipStream_t stream) {
  const float* hs = (const float*)d_in[0];
  const float* w1 = (const float*)d_in[1];
  const float* b1 = (const float*)d_in[2];
  const float* w2 = (const float*)d_in[3];
  const float* b2 = (const float*)d_in[4];
  float* out = (float*)d_out;

  dim3 grid(Nn / 64, Nn / 64, 16);   // (j-tiles, i-tiles, b) = 256 blocks
  fused_kernel<<<grid, 256, 0, stream>>>(hs, w1, b1, w2, b2, out);
}